// Round 11
// baseline (28.639 us; speedup 1.0000x reference)
//
#include <hip/hip_runtime.h>

#define NPTS  4096
#define BQ    16
#define NT    256
#define SEG   4
#define SEGN  (NPTS / SEG)       // 1024 inner points per segment
#define NT32  (SEGN / 32)        // 32 inner tiles (32 points each)
#define WC    4                  // column-tiles (32 cols each) per wave
#define WCOLS (WC * 32)          // 128 cols per wave
#define BCOLS (4 * WCOLS)        // 512 cols per block (4 waves)
#define NCOMB 128                // comb blocks

typedef short bhalf8   __attribute__((ext_vector_type(8)));   // 8 bf16 (4 VGPRs)
typedef float floatx16 __attribute__((ext_vector_type(16)));  // 32x32 MFMA acc

__device__ __forceinline__ short f2bf(float f) {
    unsigned u = __float_as_uint(f);
    unsigned r = (u + 0x7FFFu + ((u >> 16) & 1u)) >> 16;   // RNE
    return (short)r;
}
__device__ __forceinline__ float bf2f(short s) {
    return __uint_as_float(((unsigned)(unsigned short)s) << 16);
}

// Pass 1 (MFMA 32x32x16): one MFMA = 32 inner pts x 32 outer cols, D = FULL
// squared distance (xx, yy folded via split-bf16 slots). Verified R10.
// Block (0,0,0) additionally zeroes the int64 accumulator + ticket counter
// for pass 2 (stream order makes this visible before pass 2 starts).
// grid (8, 4, 32) = 1024 blocks, 4/CU.
__global__ __launch_bounds__(NT, 4)
void chamfer_mfma_kernel(const float* __restrict__ preds,
                         const float* __restrict__ gts,
                         float* __restrict__ partial,
                         unsigned long long* __restrict__ acc)
{
    __shared__ bhalf8 s_frag[NT32 * 64];   // 32 KB

    const int cb  = blockIdx.x;   // 0..7
    const int seg = blockIdx.y;   // 0..3
    const int bd  = blockIdx.z;   // 0..31
    const int dir = bd >> 4;
    const int b   = bd & 15;

    if (cb == 0 && seg == 0 && bd == 0 && threadIdx.x < 2)
        acc[threadIdx.x] = 0ULL;   // [0]=fixed-point sum, [1]=ticket counter

    const float* outer = (dir == 0) ? preds : gts;
    const float* inner = (dir == 0) ? gts   : preds;
    const float* ob = outer + (size_t)b * NPTS * 3;
    const float* ib = inner + (size_t)b * NPTS * 3 + (size_t)seg * SEGN * 3;

    const short one = (short)0x3F80;   // bf16 1.0

    // ---- stage A fragments (inner points) ----
    for (int p = (int)threadIdx.x; p < SEGN; p += NT) {
        const float x0 = ib[p * 3 + 0], x1 = ib[p * 3 + 1], x2 = ib[p * 3 + 2];
        const float a0 = -2.0f * x0, a1 = -2.0f * x1, a2 = -2.0f * x2;
        const short h0 = f2bf(a0), h1 = f2bf(a1), h2 = f2bf(a2);
        const short l0 = f2bf(a0 - bf2f(h0));
        const short l1 = f2bf(a1 - bf2f(h1));
        const short l2 = f2bf(a2 - bf2f(h2));
        const float xx = x0 * x0 + x1 * x1 + x2 * x2;
        const short xh = f2bf(xx);
        const short xl = f2bf(xx - bf2f(xh));
        bhalf8 e0, e1;
        e0[0] = h0; e0[1] = h1; e0[2] = h2; e0[3] = l0;
        e0[4] = l1; e0[5] = l2; e0[6] = xh;  e0[7] = xl;
        e1[0] = h0; e1[1] = h1; e1[2] = h2; e1[3] = l0;
        e1[4] = l1; e1[5] = l2; e1[6] = one; e1[7] = one;
        const int t = p >> 5, r = p & 31;
        s_frag[t * 64 + r]      = e0;   // k-group 0 rows (lanes 0-31)
        s_frag[t * 64 + 32 + r] = e1;   // k-group 1 rows (lanes 32-63)
    }

    const int wv   = (int)threadIdx.x >> 6;
    const int lane = (int)threadIdx.x & 63;
    const int g    = lane >> 5;          // k-group 0..1
    const int colbase = cb * BCOLS + wv * WCOLS;

    bhalf8 bfrag[WC];
#pragma unroll
    for (int ct = 0; ct < WC; ++ct) {
        const int col = colbase + ct * 32 + (lane & 31);
        const float y0 = ob[col * 3 + 0], y1 = ob[col * 3 + 1], y2 = ob[col * 3 + 2];
        const short h0 = f2bf(y0), h1 = f2bf(y1), h2 = f2bf(y2);
        bhalf8 f;
        if (g == 0) {          // k 0-7: [yh(3), yh(3), 1, 1]
            f[0] = h0; f[1] = h1; f[2] = h2; f[3] = h0; f[4] = h1; f[5] = h2;
            f[6] = one; f[7] = one;
        } else {               // k 8-15: [yl(3), yl(3), yyh, yyl]
            const short q0 = f2bf(y0 - bf2f(h0));
            const short q1 = f2bf(y1 - bf2f(h1));
            const short q2 = f2bf(y2 - bf2f(h2));
            const float yy = y0 * y0 + y1 * y1 + y2 * y2;
            const short yh = f2bf(yy);
            const short yl = f2bf(yy - bf2f(yh));
            f[0] = q0; f[1] = q1; f[2] = q2; f[3] = q0; f[4] = q1; f[5] = q2;
            f[6] = yh; f[7] = yl;
        }
        bfrag[ct] = f;
    }
    __syncthreads();

    float accm[WC];
#pragma unroll
    for (int ct = 0; ct < WC; ++ct) accm[ct] = 3.0e38f;

    const floatx16 zacc = {0,0,0,0,0,0,0,0,0,0,0,0,0,0,0,0};

#pragma unroll 2
    for (int t = 0; t < NT32; ++t) {
        const bhalf8 a = s_frag[t * 64 + lane];
#pragma unroll
        for (int ct = 0; ct < WC; ++ct) {
            const floatx16 c = __builtin_amdgcn_mfma_f32_32x32x16_bf16(a, bfrag[ct], zacc, 0, 0, 0);
            const float m0 = fminf(fminf(c[0],  c[1]),  c[2]);
            const float m1 = fminf(fminf(c[3],  c[4]),  c[5]);
            const float m2 = fminf(fminf(c[6],  c[7]),  c[8]);
            const float m3 = fminf(fminf(c[9],  c[10]), c[11]);
            const float m4 = fminf(fminf(c[12], c[13]), c[14]);
            const float m5 = fminf(fminf(m0, m1), m2);
            const float m6 = fminf(fminf(m3, m4), c[15]);
            accm[ct] = fminf(fminf(m5, m6), accm[ct]);
        }
    }

#pragma unroll
    for (int ct = 0; ct < WC; ++ct) {
        float v = accm[ct];
        v = fminf(v, __shfl_xor(v, 32, 64));
        if (lane < 32) {
            const int col = colbase + ct * 32 + lane;
            partial[((size_t)bd * NPTS + col) * SEG + seg] = v;
        }
    }
}

// Pass 2 (fused comb+final): 131072 slots; min over SEG=4 per slot, block
// tree-reduce, int64 fixed-point atomicAdd (exactly commutative -> bitwise
// deterministic), last-ticket block writes the scaled output.
__global__ __launch_bounds__(NT)
void chamfer_comb_kernel(const float* __restrict__ partial,
                         unsigned long long* __restrict__ acc,
                         float* __restrict__ out)
{
    __shared__ float s_red[NT];
    float sum = 0.0f;
#pragma unroll
    for (int i = 0; i < 4; ++i) {
        const int slot = (int)blockIdx.x * 1024 + i * NT + (int)threadIdx.x;
        const float4 p = ((const float4*)partial)[slot];
        sum += fminf(fminf(p.x, p.y), fminf(p.z, p.w));
    }
    s_red[threadIdx.x] = sum;
    __syncthreads();
#pragma unroll
    for (int s = NT / 2; s > 0; s >>= 1) {
        if ((int)threadIdx.x < s) s_red[threadIdx.x] += s_red[threadIdx.x + s];
        __syncthreads();
    }
    if (threadIdx.x == 0) {
        const long long fx = (long long)llrint((double)s_red[0] * 4294967296.0);
        atomicAdd(&acc[0], (unsigned long long)fx);
        __threadfence();
        const unsigned long long t = atomicAdd(&acc[1], 1ULL);
        if (t == (unsigned long long)(NCOMB - 1)) {
            const unsigned long long total = atomicAdd(&acc[0], 0ULL);
            const double v = (double)(long long)total *
                             (1.0 / 4294967296.0) * (1.0 / (double)(BQ * NPTS));
            out[0] = (float)v;
        }
    }
}

extern "C" void kernel_launch(void* const* d_in, const int* in_sizes, int n_in,
                              void* d_out, int out_size, void* d_ws, size_t ws_size,
                              hipStream_t stream)
{
    const float* preds = (const float*)d_in[0];
    const float* gts   = (const float*)d_in[1];
    float* out     = (float*)d_out;
    float* partial = (float*)d_ws;                                      // 2 MB
    unsigned long long* acc =
        (unsigned long long*)(partial + (size_t)2 * BQ * NPTS * SEG);   // +2 u64

    dim3 grid1(NPTS / BCOLS, SEG, 2 * BQ);   // (8, 4, 32) = 1024 blocks
    chamfer_mfma_kernel<<<grid1, NT, 0, stream>>>(preds, gts, partial, acc);
    chamfer_comb_kernel<<<NCOMB, NT, 0, stream>>>(partial, acc, out);
}

// Round 12
// 28.636 us; speedup vs baseline: 1.0001x; 1.0001x over previous
//
#include <hip/hip_runtime.h>

#define NPTS  4096
#define BQ    16
#define NT    256
#define SEG   4
#define SEGN  (NPTS / SEG)       // 1024 inner points per segment
#define NT32  (SEGN / 32)        // 32 inner tiles (32 points each)
#define WC    4                  // column-tiles (32 cols each) per wave
#define WCOLS (WC * 32)          // 128 cols per wave
#define BCOLS (4 * WCOLS)        // 512 cols per block (4 waves)
#define NCOMB 128                // comb blocks

typedef short bhalf8   __attribute__((ext_vector_type(8)));   // 8 bf16 (4 VGPRs)
typedef float floatx16 __attribute__((ext_vector_type(16)));  // 32x32 MFMA acc

__device__ __forceinline__ short f2bf(float f) {
    unsigned u = __float_as_uint(f);
    unsigned r = (u + 0x7FFFu + ((u >> 16) & 1u)) >> 16;   // RNE
    return (short)r;
}
__device__ __forceinline__ float bf2f(short s) {
    return __uint_as_float(((unsigned)(unsigned short)s) << 16);
}

// Pass 1 (MFMA 32x32x16), R10-verified body. ONLY change vs R11:
// __launch_bounds__(256, 2) — cap 256 VGPR instead of 128. Theory: the
// 128-VGPR cap forced spills / AGPR round-trips for the 16-wide MFMA
// results (multiple live under unroll 2 x WC=4). 2 blocks/CU = 8 waves/CU,
// the occupancy at which R4's VALU kernel hit 97% VALUBusy.
// grid (8, 4, 32) = 1024 blocks = exactly 2 dispatch rounds.
__global__ __launch_bounds__(NT, 2)
void chamfer_mfma_kernel(const float* __restrict__ preds,
                         const float* __restrict__ gts,
                         float* __restrict__ partial,
                         unsigned long long* __restrict__ acc)
{
    __shared__ bhalf8 s_frag[NT32 * 64];   // 32 KB

    const int cb  = blockIdx.x;   // 0..7
    const int seg = blockIdx.y;   // 0..3
    const int bd  = blockIdx.z;   // 0..31
    const int dir = bd >> 4;
    const int b   = bd & 15;

    if (cb == 0 && seg == 0 && bd == 0 && threadIdx.x < 2)
        acc[threadIdx.x] = 0ULL;   // [0]=fixed-point sum, [1]=ticket counter

    const float* outer = (dir == 0) ? preds : gts;
    const float* inner = (dir == 0) ? gts   : preds;
    const float* ob = outer + (size_t)b * NPTS * 3;
    const float* ib = inner + (size_t)b * NPTS * 3 + (size_t)seg * SEGN * 3;

    const short one = (short)0x3F80;   // bf16 1.0

    // ---- stage A fragments (inner points) ----
    for (int p = (int)threadIdx.x; p < SEGN; p += NT) {
        const float x0 = ib[p * 3 + 0], x1 = ib[p * 3 + 1], x2 = ib[p * 3 + 2];
        const float a0 = -2.0f * x0, a1 = -2.0f * x1, a2 = -2.0f * x2;
        const short h0 = f2bf(a0), h1 = f2bf(a1), h2 = f2bf(a2);
        const short l0 = f2bf(a0 - bf2f(h0));
        const short l1 = f2bf(a1 - bf2f(h1));
        const short l2 = f2bf(a2 - bf2f(h2));
        const float xx = x0 * x0 + x1 * x1 + x2 * x2;
        const short xh = f2bf(xx);
        const short xl = f2bf(xx - bf2f(xh));
        bhalf8 e0, e1;
        e0[0] = h0; e0[1] = h1; e0[2] = h2; e0[3] = l0;
        e0[4] = l1; e0[5] = l2; e0[6] = xh;  e0[7] = xl;
        e1[0] = h0; e1[1] = h1; e1[2] = h2; e1[3] = l0;
        e1[4] = l1; e1[5] = l2; e1[6] = one; e1[7] = one;
        const int t = p >> 5, r = p & 31;
        s_frag[t * 64 + r]      = e0;   // k-group 0 rows (lanes 0-31)
        s_frag[t * 64 + 32 + r] = e1;   // k-group 1 rows (lanes 32-63)
    }

    const int wv   = (int)threadIdx.x >> 6;
    const int lane = (int)threadIdx.x & 63;
    const int g    = lane >> 5;          // k-group 0..1
    const int colbase = cb * BCOLS + wv * WCOLS;

    bhalf8 bfrag[WC];
#pragma unroll
    for (int ct = 0; ct < WC; ++ct) {
        const int col = colbase + ct * 32 + (lane & 31);
        const float y0 = ob[col * 3 + 0], y1 = ob[col * 3 + 1], y2 = ob[col * 3 + 2];
        const short h0 = f2bf(y0), h1 = f2bf(y1), h2 = f2bf(y2);
        bhalf8 f;
        if (g == 0) {          // k 0-7: [yh(3), yh(3), 1, 1]
            f[0] = h0; f[1] = h1; f[2] = h2; f[3] = h0; f[4] = h1; f[5] = h2;
            f[6] = one; f[7] = one;
        } else {               // k 8-15: [yl(3), yl(3), yyh, yyl]
            const short q0 = f2bf(y0 - bf2f(h0));
            const short q1 = f2bf(y1 - bf2f(h1));
            const short q2 = f2bf(y2 - bf2f(h2));
            const float yy = y0 * y0 + y1 * y1 + y2 * y2;
            const short yh = f2bf(yy);
            const short yl = f2bf(yy - bf2f(yh));
            f[0] = q0; f[1] = q1; f[2] = q2; f[3] = q0; f[4] = q1; f[5] = q2;
            f[6] = yh; f[7] = yl;
        }
        bfrag[ct] = f;
    }
    __syncthreads();

    float accm[WC];
#pragma unroll
    for (int ct = 0; ct < WC; ++ct) accm[ct] = 3.0e38f;

    const floatx16 zacc = {0,0,0,0,0,0,0,0,0,0,0,0,0,0,0,0};

#pragma unroll 2
    for (int t = 0; t < NT32; ++t) {
        const bhalf8 a = s_frag[t * 64 + lane];
#pragma unroll
        for (int ct = 0; ct < WC; ++ct) {
            const floatx16 c = __builtin_amdgcn_mfma_f32_32x32x16_bf16(a, bfrag[ct], zacc, 0, 0, 0);
            const float m0 = fminf(fminf(c[0],  c[1]),  c[2]);
            const float m1 = fminf(fminf(c[3],  c[4]),  c[5]);
            const float m2 = fminf(fminf(c[6],  c[7]),  c[8]);
            const float m3 = fminf(fminf(c[9],  c[10]), c[11]);
            const float m4 = fminf(fminf(c[12], c[13]), c[14]);
            const float m5 = fminf(fminf(m0, m1), m2);
            const float m6 = fminf(fminf(m3, m4), c[15]);
            accm[ct] = fminf(fminf(m5, m6), accm[ct]);
        }
    }

#pragma unroll
    for (int ct = 0; ct < WC; ++ct) {
        float v = accm[ct];
        v = fminf(v, __shfl_xor(v, 32, 64));
        if (lane < 32) {
            const int col = colbase + ct * 32 + lane;
            partial[((size_t)bd * NPTS + col) * SEG + seg] = v;
        }
    }
}

// Pass 2 (fused comb+final): min over SEG=4 per slot, block tree-reduce,
// int64 fixed-point atomicAdd (bitwise deterministic), last block writes out.
__global__ __launch_bounds__(NT)
void chamfer_comb_kernel(const float* __restrict__ partial,
                         unsigned long long* __restrict__ acc,
                         float* __restrict__ out)
{
    __shared__ float s_red[NT];
    float sum = 0.0f;
#pragma unroll
    for (int i = 0; i < 4; ++i) {
        const int slot = (int)blockIdx.x * 1024 + i * NT + (int)threadIdx.x;
        const float4 p = ((const float4*)partial)[slot];
        sum += fminf(fminf(p.x, p.y), fminf(p.z, p.w));
    }
    s_red[threadIdx.x] = sum;
    __syncthreads();
#pragma unroll
    for (int s = NT / 2; s > 0; s >>= 1) {
        if ((int)threadIdx.x < s) s_red[threadIdx.x] += s_red[threadIdx.x + s];
        __syncthreads();
    }
    if (threadIdx.x == 0) {
        const long long fx = (long long)llrint((double)s_red[0] * 4294967296.0);
        atomicAdd(&acc[0], (unsigned long long)fx);
        __threadfence();
        const unsigned long long t = atomicAdd(&acc[1], 1ULL);
        if (t == (unsigned long long)(NCOMB - 1)) {
            const unsigned long long total = atomicAdd(&acc[0], 0ULL);
            const double v = (double)(long long)total *
                             (1.0 / 4294967296.0) * (1.0 / (double)(BQ * NPTS));
            out[0] = (float)v;
        }
    }
}

extern "C" void kernel_launch(void* const* d_in, const int* in_sizes, int n_in,
                              void* d_out, int out_size, void* d_ws, size_t ws_size,
                              hipStream_t stream)
{
    const float* preds = (const float*)d_in[0];
    const float* gts   = (const float*)d_in[1];
    float* out     = (float*)d_out;
    float* partial = (float*)d_ws;                                      // 2 MB
    unsigned long long* acc =
        (unsigned long long*)(partial + (size_t)2 * BQ * NPTS * SEG);   // +2 u64

    dim3 grid1(NPTS / BCOLS, SEG, 2 * BQ);   // (8, 4, 32) = 1024 blocks
    chamfer_mfma_kernel<<<grid1, NT, 0, stream>>>(preds, gts, partial, acc);
    chamfer_comb_kernel<<<NCOMB, NT, 0, stream>>>(partial, acc, out);
}